// Round 3
// baseline (539.564 us; speedup 1.0000x reference)
//
#include <hip/hip_runtime.h>
#include <hip/hip_fp16.h>
#include <math.h>

#define DIM 768
#define NTOK 1024
#define NBATCH 16
#define BNR (NBATCH * NTOK)   // 16384 rows

typedef _Float16 f16x8 __attribute__((ext_vector_type(8)));
typedef float f32x4 __attribute__((ext_vector_type(4)));

// async global->LDS, 16B per lane, LDS dest = wave-uniform base + lane*16
__device__ __forceinline__ void gl2lds16(const void* g, void* l) {
    __builtin_amdgcn_global_load_lds(
        (const __attribute__((address_space(1))) void*)g,
        (__attribute__((address_space(3))) void*)l, 16, 0, 0);
}

// branch-free exact-gelu: erf via Abramowitz-Stegun 7.1.26 (|abs err| <= 1.5e-7)
__device__ __forceinline__ float gelu_fast(float z) {
    const float s = z * 0.70710678118654752f;
    const float ax = fabsf(s);
    const float t = __builtin_amdgcn_rcpf(1.0f + 0.3275911f * ax);
    const float poly = t * (0.254829592f + t * (-0.284496736f +
                       t * (1.421413741f + t * (-1.453152027f + t * 1.061405429f))));
    const float e = __expf(-ax * ax);
    float erfv = 1.0f - poly * e;
    erfv = copysignf(erfv, s);
    return 0.5f * z * (1.0f + erfv);
}

__device__ __forceinline__ float block_sum(float v, float* sbuf) {
    #pragma unroll
    for (int o = 32; o > 0; o >>= 1) v += __shfl_down(v, o, 64);
    const int lane = threadIdx.x & 63, w = threadIdx.x >> 6;
    if (lane == 0) sbuf[w] = v;
    __syncthreads();
    const float r = sbuf[0] + sbuf[1] + sbuf[2] + sbuf[3];
    __syncthreads();
    return r;
}

// avg over tokens, split 8-way over the token axis for parallelism
__global__ __launch_bounds__(256) void avg_kernel(const float* __restrict__ x,
                                                  float* __restrict__ avgx) {
    const int d = blockIdx.x * 256 + threadIdx.x;
    const int b = blockIdx.y;
    const int n0 = blockIdx.z * 128;
    const float* xp = x + (size_t)b * NTOK * DIM + (size_t)n0 * DIM + d;
    float s = 0.0f;
    for (int n = 0; n < 128; ++n) s += xp[(size_t)n * DIM];
    atomicAdd(&avgx[b * DIM + d], s * (1.0f / NTOK));
}

// LN -> sigmoid -> A = avg_x*sig, stored fp16; sq computed from fp16-rounded A
__global__ __launch_bounds__(256) void ln_sig_kernel(
    const float* __restrict__ x, const float* __restrict__ gamma,
    const float* __restrict__ beta, const float* __restrict__ avgx,
    __half* __restrict__ Ah, float* __restrict__ sq)
{
    __shared__ float sbuf[4];
    const int row = blockIdx.x;
    const int b = row >> 10;
    const int tid = threadIdx.x;
    const float* xr = x + (size_t)row * DIM;
    float v[3];
    #pragma unroll
    for (int i = 0; i < 3; ++i) v[i] = xr[tid + 256 * i];
    const float mu = block_sum(v[0] + v[1] + v[2], sbuf) * (1.0f / DIM);
    float ss = 0.0f;
    #pragma unroll
    for (int i = 0; i < 3; ++i) { const float d = v[i] - mu; ss += d * d; }
    const float var = block_sum(ss, sbuf) * (1.0f / DIM);
    const float rstd = rsqrtf(var + 1e-5f);
    const float* ag = avgx + b * DIM;
    float qs = 0.0f;
    #pragma unroll
    for (int i = 0; i < 3; ++i) {
        const int d = tid + 256 * i;
        const float ln = (v[i] - mu) * rstd * gamma[d] + beta[d];
        const float sg = 1.0f / (1.0f + expf(-ln));
        const float a = ag[d] * sg;
        const __half h = __float2half(a);
        const float ar = __half2float(h);
        Ah[(size_t)row * DIM + d] = h;
        qs += ar * ar;
    }
    const float tot = block_sum(qs, sbuf);
    if (tid == 0) sq[row] = tot;
}

// fp32 [K][N] -> fp16 [N][K] tiled transpose
__global__ __launch_bounds__(256) void wconv(const float* __restrict__ w,
                                             __half* __restrict__ wT, int K, int N)
{
    __shared__ float t[64][65];
    const int k0 = blockIdx.y * 64, n0 = blockIdx.x * 64;
    const int tid = threadIdx.x;
    const int r = tid >> 4, c4 = (tid & 15) * 4;
    #pragma unroll
    for (int p = 0; p < 4; ++p) {
        const int rr = p * 16 + r;
        const float4 v = *(const float4*)&w[(size_t)(k0 + rr) * N + n0 + c4];
        t[rr][c4] = v.x; t[rr][c4 + 1] = v.y; t[rr][c4 + 2] = v.z; t[rr][c4 + 3] = v.w;
    }
    __syncthreads();
    #pragma unroll
    for (int p = 0; p < 4; ++p) {
        const int nn = p * 16 + r;
        ushort4 pk;
        pk.x = __half_as_ushort(__float2half(t[c4 + 0][nn]));
        pk.y = __half_as_ushort(__float2half(t[c4 + 1][nn]));
        pk.z = __half_as_ushort(__float2half(t[c4 + 2][nn]));
        pk.w = __half_as_ushort(__float2half(t[c4 + 3][nn]));
        *(ushort4*)&wT[(size_t)(n0 + nn) * K + k0 + c4] = pk;
    }
}

__global__ __launch_bounds__(256) void xm_kernel(const float* __restrict__ x,
                                                 const float* __restrict__ m,
                                                 __half* __restrict__ xmH) {
    const int row = blockIdx.x;
    const float mv = m[row];
    #pragma unroll
    for (int i = 0; i < 3; ++i) {
        const int d = threadIdx.x + i * 256;
        xmH[(size_t)row * DIM + d] = __float2half(x[(size_t)row * DIM + d] + mv);
    }
}

// ---- MFMA fp16 GEMM, 64x128 tile, BK=32, 4 waves 2x2 (wave=32x64) ----
// LDS layout is k-octet-major: [k8][row] cells of 8 halves (16B) -> conflict-free
// ds_read_b128 AND legal wave-uniform global_load_lds staging (wave w stages octet w).
// grid = (rows=256, cols=6): col-blocks of one row-stripe share id mod 8 -> same XCD.
// EPI 0: m1=gelu(z)->fp16 ; 1: h3=m1h*x*gelu(z)->fp16 ; 2: h4=x*gelu(z)->fp16 ; 3: out=gelu(z)->fp32
template<bool CAT, int EPI>
__global__ __launch_bounds__(256, 6) void gemm16(
    const __half* __restrict__ A0, const __half* __restrict__ A1, const int K,
    const __half* __restrict__ BT, const float* __restrict__ bias,
    const float* __restrict__ xin, const __half* __restrict__ m1h,
    __half* __restrict__ outH, float* __restrict__ outF)
{
    __shared__ _Float16 As[4 * 64 * 8];     // [k8][row 0..63][8]
    __shared__ _Float16 Bs[4 * 128 * 8];    // [k8][row 0..127][8]
    const int tid = threadIdx.x;
    const int w = tid >> 6, lane = tid & 63;
    const int wu = __builtin_amdgcn_readfirstlane(w);
    const int wr = w >> 1, wc = w & 1;
    const int R0 = blockIdx.x * 64, J0 = blockIdx.y * 128;
    const int rs = CAT ? DIM : K;           // A row stride (halves)

    f32x4 acc[2][4];
    #pragma unroll
    for (int mt = 0; mt < 2; ++mt)
        #pragma unroll
        for (int nt = 0; nt < 4; ++nt) {
            f32x4 z = {0.0f, 0.0f, 0.0f, 0.0f};
            acc[mt][nt] = z;
        }

    for (int k0 = 0; k0 < K; k0 += 32) {
        const __half* Ab = (CAT && k0 >= DIM) ? (A1 + (k0 - DIM)) : (A0 + k0);
        // wave w stages k-octet w: A rows 0..63 (1 call), B rows 0..127 (2 calls)
        gl2lds16(Ab + (size_t)(R0 + lane) * rs + wu * 8, &As[(wu * 64) * 8]);
        #pragma unroll
        for (int i = 0; i < 2; ++i)
            gl2lds16(BT + (size_t)(J0 + i * 64 + lane) * K + k0 + wu * 8,
                     &Bs[(wu * 128 + i * 64) * 8]);
        __syncthreads();
        f16x8 af[2], bf[4];
        #pragma unroll
        for (int mt = 0; mt < 2; ++mt)
            af[mt] = *(const f16x8*)&As[((lane >> 4) * 64 + wr * 32 + mt * 16 + (lane & 15)) * 8];
        #pragma unroll
        for (int nt = 0; nt < 4; ++nt)
            bf[nt] = *(const f16x8*)&Bs[((lane >> 4) * 128 + wc * 64 + nt * 16 + (lane & 15)) * 8];
        #pragma unroll
        for (int mt = 0; mt < 2; ++mt)
            #pragma unroll
            for (int nt = 0; nt < 4; ++nt)
                acc[mt][nt] = __builtin_amdgcn_mfma_f32_16x16x32_f16(af[mt], bf[nt], acc[mt][nt], 0, 0, 0);
        __syncthreads();
    }

    // C/D layout: col = lane&15, row = (lane>>4)*4 + reg
    #pragma unroll
    for (int mt = 0; mt < 2; ++mt) {
        #pragma unroll
        for (int nt = 0; nt < 4; ++nt) {
            const int col = J0 + wc * 64 + nt * 16 + (lane & 15);
            const float bv = bias[col];
            #pragma unroll
            for (int r = 0; r < 4; ++r) {
                const int row = R0 + wr * 32 + mt * 16 + (lane >> 4) * 4 + r;
                const size_t off = (size_t)row * DIM + col;
                const float g = gelu_fast(acc[mt][nt][r] + bv);
                if (EPI == 0) {
                    outH[off] = __float2half(g);
                } else if (EPI == 1) {
                    outH[off] = __float2half(__half2float(m1h[off]) * xin[off] * g);
                } else if (EPI == 2) {
                    outH[off] = __float2half(xin[off] * g);
                } else {
                    outF[off] = g;
                }
            }
        }
    }
}

// dist row-max: grid (batch=16, 8, 8) so batch == id mod 8 区 -> per-XCD A locality.
__global__ __launch_bounds__(256, 4) void dist16(const __half* __restrict__ Ah,
                                                 const float* __restrict__ sq,
                                                 float* __restrict__ m)
{
    __shared__ _Float16 As[4 * 128 * 8];
    __shared__ _Float16 Bs[4 * 128 * 8];
    const int tid = threadIdx.x;
    const int w = tid >> 6, lane = tid & 63;
    const int wu = __builtin_amdgcn_readfirstlane(w);
    const int wr = w >> 1, wc = w & 1;
    const int base = blockIdx.x * NTOK;
    const int I0 = blockIdx.y * 128, J0 = blockIdx.z * 128;

    f32x4 acc[4][4];
    #pragma unroll
    for (int mt = 0; mt < 4; ++mt)
        #pragma unroll
        for (int nt = 0; nt < 4; ++nt) {
            f32x4 z = {0.0f, 0.0f, 0.0f, 0.0f};
            acc[mt][nt] = z;
        }

    for (int k0 = 0; k0 < DIM; k0 += 32) {
        #pragma unroll
        for (int i = 0; i < 2; ++i) {
            gl2lds16(Ah + (size_t)(base + I0 + i * 64 + lane) * DIM + k0 + wu * 8,
                     &As[(wu * 128 + i * 64) * 8]);
            gl2lds16(Ah + (size_t)(base + J0 + i * 64 + lane) * DIM + k0 + wu * 8,
                     &Bs[(wu * 128 + i * 64) * 8]);
        }
        __syncthreads();
        f16x8 af[4], bf[4];
        #pragma unroll
        for (int mt = 0; mt < 4; ++mt)
            af[mt] = *(const f16x8*)&As[((lane >> 4) * 128 + wr * 64 + mt * 16 + (lane & 15)) * 8];
        #pragma unroll
        for (int nt = 0; nt < 4; ++nt)
            bf[nt] = *(const f16x8*)&Bs[((lane >> 4) * 128 + wc * 64 + nt * 16 + (lane & 15)) * 8];
        #pragma unroll
        for (int mt = 0; mt < 4; ++mt)
            #pragma unroll
            for (int nt = 0; nt < 4; ++nt)
                acc[mt][nt] = __builtin_amdgcn_mfma_f32_16x16x32_f16(af[mt], bf[nt], acc[mt][nt], 0, 0, 0);
        __syncthreads();
    }

    #pragma unroll
    for (int mt = 0; mt < 4; ++mt) {
        float sqi[4];
        #pragma unroll
        for (int r = 0; r < 4; ++r)
            sqi[r] = sq[base + I0 + wr * 64 + mt * 16 + (lane >> 4) * 4 + r];
        float vmax[4] = {0.0f, 0.0f, 0.0f, 0.0f};
        #pragma unroll
        for (int nt = 0; nt < 4; ++nt) {
            const float sqj = sq[base + J0 + wc * 64 + nt * 16 + (lane & 15)];
            #pragma unroll
            for (int r = 0; r < 4; ++r) {
                const float d2 = sqi[r] + sqj - 2.0f * acc[mt][nt][r];
                vmax[r] = fmaxf(vmax[r], sqrtf(fmaxf(d2, 1e-12f)));
            }
        }
        #pragma unroll
        for (int r = 0; r < 4; ++r) {
            float v = vmax[r];
            v = fmaxf(v, __shfl_xor(v, 1, 64));
            v = fmaxf(v, __shfl_xor(v, 2, 64));
            v = fmaxf(v, __shfl_xor(v, 4, 64));
            v = fmaxf(v, __shfl_xor(v, 8, 64));
            if ((lane & 15) == 0)
                atomicMax((unsigned int*)&m[base + I0 + wr * 64 + mt * 16 + (lane >> 4) * 4 + r],
                          __float_as_uint(v));
        }
    }
}

extern "C" void kernel_launch(void* const* d_in, const int* in_sizes, int n_in,
                              void* d_out, int out_size, void* d_ws, size_t ws_size,
                              hipStream_t stream)
{
    const float* x     = (const float*)d_in[0];
    const float* gamma = (const float*)d_in[1];
    const float* beta  = (const float*)d_in[2];
    const float* w1    = (const float*)d_in[3];
    const float* b1    = (const float*)d_in[4];
    const float* w2    = (const float*)d_in[5];
    const float* b2    = (const float*)d_in[6];
    const float* w3    = (const float*)d_in[7];
    const float* b3    = (const float*)d_in[8];
    const float* w4    = (const float*)d_in[9];
    const float* b4    = (const float*)d_in[10];
    float* out = (float*)d_out;
    float* ws  = (float*)d_ws;

    // ws: avgx[12288] sq[16384] m[16384] | w1T..w4T fp16 | P0,P1 fp16 [BNR*DIM]
    float* avgx = ws;
    float* sq   = ws + 12288;
    float* mbuf = sq + 16384;
    __half* w1T = (__half*)(mbuf + 16384);
    __half* w2T = w1T + (size_t)1536 * 768;
    __half* w3T = w2T + (size_t)768 * 768;
    __half* w4T = w3T + (size_t)768 * 768;
    __half* P0  = w4T + (size_t)768 * 768;            // m1H, later h4H
    __half* P1  = P0 + (size_t)BNR * DIM;             // h3H
    // d_out hosts the two L1-only fp16 operands (dead before L4 writes out)
    __half* Ah  = (__half*)d_out;
    __half* xmH = Ah + (size_t)BNR * DIM;

    hipMemsetAsync(avgx, 0, 12288 * sizeof(float), stream);
    hipMemsetAsync(mbuf, 0, BNR * sizeof(float), stream);
    wconv<<<dim3(12, 24), 256, 0, stream>>>(w1, w1T, 1536, 768);
    wconv<<<dim3(12, 12), 256, 0, stream>>>(w2, w2T, 768, 768);
    wconv<<<dim3(12, 12), 256, 0, stream>>>(w3, w3T, 768, 768);
    wconv<<<dim3(12, 12), 256, 0, stream>>>(w4, w4T, 768, 768);
    avg_kernel<<<dim3(3, NBATCH, 8), 256, 0, stream>>>(x, avgx);
    ln_sig_kernel<<<BNR, 256, 0, stream>>>(x, gamma, beta, avgx, Ah, sq);
    dist16<<<dim3(NBATCH, 8, 8), 256, 0, stream>>>(Ah, sq, mbuf);
    xm_kernel<<<BNR, 256, 0, stream>>>(x, mbuf, xmH);
    // L1: m1 = gelu(cat @ w1 + b1)
    gemm16<true, 0><<<dim3(256, 6), 256, 0, stream>>>(
        Ah, xmH, 2 * DIM, w1T, b1, nullptr, nullptr, P0, nullptr);
    // L2: h3 = m1 * x * gelu(m1 @ w2 + b2)
    gemm16<false, 1><<<dim3(256, 6), 256, 0, stream>>>(
        P0, nullptr, DIM, w2T, b2, x, P0, P1, nullptr);
    // L3: h4 = x * gelu(h3 @ w3 + b3)
    gemm16<false, 2><<<dim3(256, 6), 256, 0, stream>>>(
        P1, nullptr, DIM, w3T, b3, x, nullptr, P0, nullptr);
    // L4: out = gelu(h4 @ w4 + b4)
    gemm16<false, 3><<<dim3(256, 6), 256, 0, stream>>>(
        P0, nullptr, DIM, w4T, b4, x, nullptr, nullptr, out);
}

// Round 4
// 352.665 us; speedup vs baseline: 1.5300x; 1.5300x over previous
//
#include <hip/hip_runtime.h>
#include <hip/hip_fp16.h>
#include <math.h>

#define DIM 768
#define NTOK 1024
#define NBATCH 16
#define BNR (NBATCH * NTOK)   // 16384 rows

typedef _Float16 f16x8 __attribute__((ext_vector_type(8)));
typedef float f32x4 __attribute__((ext_vector_type(4)));

// async global->LDS, 16B per lane, LDS dest = wave-uniform base + lane*16
__device__ __forceinline__ void gl2lds16(const void* g, void* l) {
    __builtin_amdgcn_global_load_lds(
        (const __attribute__((address_space(1))) void*)g,
        (__attribute__((address_space(3))) void*)l, 16, 0, 0);
}

// branch-free exact-gelu: erf via Abramowitz-Stegun 7.1.26 (|abs err| <= 1.5e-7)
__device__ __forceinline__ float gelu_fast(float z) {
    const float s = z * 0.70710678118654752f;
    const float ax = fabsf(s);
    const float t = __builtin_amdgcn_rcpf(1.0f + 0.3275911f * ax);
    const float poly = t * (0.254829592f + t * (-0.284496736f +
                       t * (1.421413741f + t * (-1.453152027f + t * 1.061405429f))));
    const float e = __expf(-ax * ax);
    float erfv = 1.0f - poly * e;
    erfv = copysignf(erfv, s);
    return 0.5f * z * (1.0f + erfv);
}

__device__ __forceinline__ float block_sum(float v, float* sbuf) {
    #pragma unroll
    for (int o = 32; o > 0; o >>= 1) v += __shfl_down(v, o, 64);
    const int lane = threadIdx.x & 63, w = threadIdx.x >> 6;
    if (lane == 0) sbuf[w] = v;
    __syncthreads();
    const float r = sbuf[0] + sbuf[1] + sbuf[2] + sbuf[3];
    __syncthreads();
    return r;
}

// avg over tokens, split 8-way over the token axis for parallelism
__global__ __launch_bounds__(256) void avg_kernel(const float* __restrict__ x,
                                                  float* __restrict__ avgx) {
    const int d = blockIdx.x * 256 + threadIdx.x;
    const int b = blockIdx.y;
    const int n0 = blockIdx.z * 128;
    const float* xp = x + (size_t)b * NTOK * DIM + (size_t)n0 * DIM + d;
    float s = 0.0f;
    for (int n = 0; n < 128; ++n) s += xp[(size_t)n * DIM];
    atomicAdd(&avgx[b * DIM + d], s * (1.0f / NTOK));
}

// LN -> sigmoid -> A = avg_x*sig, stored fp16; sq computed from fp16-rounded A
__global__ __launch_bounds__(256) void ln_sig_kernel(
    const float* __restrict__ x, const float* __restrict__ gamma,
    const float* __restrict__ beta, const float* __restrict__ avgx,
    __half* __restrict__ Ah, float* __restrict__ sq)
{
    __shared__ float sbuf[4];
    const int row = blockIdx.x;
    const int b = row >> 10;
    const int tid = threadIdx.x;
    const float* xr = x + (size_t)row * DIM;
    float v[3];
    #pragma unroll
    for (int i = 0; i < 3; ++i) v[i] = xr[tid + 256 * i];
    const float mu = block_sum(v[0] + v[1] + v[2], sbuf) * (1.0f / DIM);
    float ss = 0.0f;
    #pragma unroll
    for (int i = 0; i < 3; ++i) { const float d = v[i] - mu; ss += d * d; }
    const float var = block_sum(ss, sbuf) * (1.0f / DIM);
    const float rstd = rsqrtf(var + 1e-5f);
    const float* ag = avgx + b * DIM;
    float qs = 0.0f;
    #pragma unroll
    for (int i = 0; i < 3; ++i) {
        const int d = tid + 256 * i;
        const float ln = (v[i] - mu) * rstd * gamma[d] + beta[d];
        const float sg = 1.0f / (1.0f + expf(-ln));
        const float a = ag[d] * sg;
        const __half h = __float2half(a);
        const float ar = __half2float(h);
        Ah[(size_t)row * DIM + d] = h;
        qs += ar * ar;
    }
    const float tot = block_sum(qs, sbuf);
    if (tid == 0) sq[row] = tot;
}

// fp32 [K][N] -> fp16 [N][K] tiled transpose
__global__ __launch_bounds__(256) void wconv(const float* __restrict__ w,
                                             __half* __restrict__ wT, int K, int N)
{
    __shared__ float t[64][65];
    const int k0 = blockIdx.y * 64, n0 = blockIdx.x * 64;
    const int tid = threadIdx.x;
    const int r = tid >> 4, c4 = (tid & 15) * 4;
    #pragma unroll
    for (int p = 0; p < 4; ++p) {
        const int rr = p * 16 + r;
        const float4 v = *(const float4*)&w[(size_t)(k0 + rr) * N + n0 + c4];
        t[rr][c4] = v.x; t[rr][c4 + 1] = v.y; t[rr][c4 + 2] = v.z; t[rr][c4 + 3] = v.w;
    }
    __syncthreads();
    #pragma unroll
    for (int p = 0; p < 4; ++p) {
        const int nn = p * 16 + r;
        ushort4 pk;
        pk.x = __half_as_ushort(__float2half(t[c4 + 0][nn]));
        pk.y = __half_as_ushort(__float2half(t[c4 + 1][nn]));
        pk.z = __half_as_ushort(__float2half(t[c4 + 2][nn]));
        pk.w = __half_as_ushort(__float2half(t[c4 + 3][nn]));
        *(ushort4*)&wT[(size_t)(n0 + nn) * K + k0 + c4] = pk;
    }
}

__global__ __launch_bounds__(256) void xm_kernel(const float* __restrict__ x,
                                                 const float* __restrict__ m,
                                                 __half* __restrict__ xmH) {
    const int row = blockIdx.x;
    const float mv = m[row];
    #pragma unroll
    for (int i = 0; i < 3; ++i) {
        const int d = threadIdx.x + i * 256;
        xmH[(size_t)row * DIM + d] = __float2half(x[(size_t)row * DIM + d] + mv);
    }
}

// ---- MFMA fp16 GEMM, 128x128 tile, BK=32, 4 waves 2x2 (wave=64x64) ----
// LDS: logical cell (row, koct) stored at halves offset row*32 + (koct^(row&3))*8.
//  - staging (global_load_lds): lane l -> dest base+l*16 == (row=l>>2, phys oct l&3);
//    lane fetches logical oct (l&3)^((l>>2)&3) -> 64B-coalesced per 4 lanes.
//  - frag ds_read_b128: 64 lanes uniform over all 8 bank-quads -> conflict-free.
// grid = (rows, cols): consecutive ids share the col-stripe -> B L2-resident.
// EPI 0: m1=gelu(z)->fp16 ; 1: h3=m1h*x*gelu(z)->fp16 ; 2: h4=x*gelu(z)->fp16 ; 3: out=gelu(z)->fp32
template<bool CAT, int EPI>
__global__ __launch_bounds__(256, 4) void gemm16(
    const __half* __restrict__ A0, const __half* __restrict__ A1, const int K,
    const __half* __restrict__ BT, const float* __restrict__ bias,
    const float* __restrict__ xin, const __half* __restrict__ m1h,
    __half* __restrict__ outH, float* __restrict__ outF)
{
    __shared__ _Float16 As[128 * 32];
    __shared__ _Float16 Bs[128 * 32];
    const int tid = threadIdx.x;
    const int w = tid >> 6, lane = tid & 63;
    const int wu = __builtin_amdgcn_readfirstlane(w);
    const int wr = w >> 1, wc = w & 1;
    const int R0 = blockIdx.x * 128, J0 = blockIdx.y * 128;
    const int rs = CAT ? DIM : K;               // A row stride (halves)
    const int srow = lane >> 2;                 // staging row within 16
    const int sk8 = (((lane & 3) ^ ((lane >> 2) & 3))) * 8;  // swizzled k-offset (halves)
    const int fx = ((lane >> 4) ^ (lane & 3)) * 8;           // frag-read swizzled oct offset

    f32x4 acc[4][4];
    #pragma unroll
    for (int mt = 0; mt < 4; ++mt)
        #pragma unroll
        for (int nt = 0; nt < 4; ++nt) {
            f32x4 z = {0.0f, 0.0f, 0.0f, 0.0f};
            acc[mt][nt] = z;
        }

    for (int k0 = 0; k0 < K; k0 += 32) {
        const __half* Ab = (CAT && k0 >= DIM) ? (A1 + (k0 - DIM)) : (A0 + k0);
        #pragma unroll
        for (int i = 0; i < 2; ++i) {
            const int rbase = i * 64 + w * 16;
            const int rbu = i * 64 + wu * 16;
            gl2lds16(Ab + (size_t)(R0 + rbase + srow) * rs + sk8, &As[rbu * 32]);
            gl2lds16(BT + (size_t)(J0 + rbase + srow) * K + k0 + sk8, &Bs[rbu * 32]);
        }
        __syncthreads();
        f16x8 af[4], bf[4];
        #pragma unroll
        for (int mt = 0; mt < 4; ++mt)
            af[mt] = *(const f16x8*)&As[(wr * 64 + mt * 16 + (lane & 15)) * 32 + fx];
        #pragma unroll
        for (int nt = 0; nt < 4; ++nt)
            bf[nt] = *(const f16x8*)&Bs[(wc * 64 + nt * 16 + (lane & 15)) * 32 + fx];
        #pragma unroll
        for (int mt = 0; mt < 4; ++mt)
            #pragma unroll
            for (int nt = 0; nt < 4; ++nt)
                acc[mt][nt] = __builtin_amdgcn_mfma_f32_16x16x32_f16(af[mt], bf[nt], acc[mt][nt], 0, 0, 0);
        __syncthreads();
    }

    // C/D layout: col = lane&15, row = (lane>>4)*4 + reg
    #pragma unroll
    for (int mt = 0; mt < 4; ++mt) {
        #pragma unroll
        for (int nt = 0; nt < 4; ++nt) {
            const int col = J0 + wc * 64 + nt * 16 + (lane & 15);
            const float bv = bias[col];
            #pragma unroll
            for (int r = 0; r < 4; ++r) {
                const int row = R0 + wr * 64 + mt * 16 + (lane >> 4) * 4 + r;
                const size_t off = (size_t)row * DIM + col;
                const float g = gelu_fast(acc[mt][nt][r] + bv);
                if (EPI == 0) {
                    outH[off] = __float2half(g);
                } else if (EPI == 1) {
                    outH[off] = __float2half(__half2float(m1h[off]) * xin[off] * g);
                } else if (EPI == 2) {
                    outH[off] = __float2half(xin[off] * g);
                } else {
                    outF[off] = g;
                }
            }
        }
    }
}

// dist row-max: 128x128 tiles, same swizzled staging; grid (batch, I, J)
__global__ __launch_bounds__(256, 4) void dist16(const __half* __restrict__ Ah,
                                                 const float* __restrict__ sq,
                                                 float* __restrict__ m)
{
    __shared__ _Float16 As[128 * 32];
    __shared__ _Float16 Bs[128 * 32];
    const int tid = threadIdx.x;
    const int w = tid >> 6, lane = tid & 63;
    const int wu = __builtin_amdgcn_readfirstlane(w);
    const int wr = w >> 1, wc = w & 1;
    const int base = blockIdx.x * NTOK;
    const int I0 = blockIdx.y * 128, J0 = blockIdx.z * 128;
    const int srow = lane >> 2;
    const int sk8 = (((lane & 3) ^ ((lane >> 2) & 3))) * 8;
    const int fx = ((lane >> 4) ^ (lane & 3)) * 8;

    f32x4 acc[4][4];
    #pragma unroll
    for (int mt = 0; mt < 4; ++mt)
        #pragma unroll
        for (int nt = 0; nt < 4; ++nt) {
            f32x4 z = {0.0f, 0.0f, 0.0f, 0.0f};
            acc[mt][nt] = z;
        }

    for (int k0 = 0; k0 < DIM; k0 += 32) {
        #pragma unroll
        for (int i = 0; i < 2; ++i) {
            const int rbase = i * 64 + w * 16;
            const int rbu = i * 64 + wu * 16;
            gl2lds16(Ah + (size_t)(base + I0 + rbase + srow) * DIM + k0 + sk8, &As[rbu * 32]);
            gl2lds16(Ah + (size_t)(base + J0 + rbase + srow) * DIM + k0 + sk8, &Bs[rbu * 32]);
        }
        __syncthreads();
        f16x8 af[4], bf[4];
        #pragma unroll
        for (int mt = 0; mt < 4; ++mt)
            af[mt] = *(const f16x8*)&As[(wr * 64 + mt * 16 + (lane & 15)) * 32 + fx];
        #pragma unroll
        for (int nt = 0; nt < 4; ++nt)
            bf[nt] = *(const f16x8*)&Bs[(wc * 64 + nt * 16 + (lane & 15)) * 32 + fx];
        #pragma unroll
        for (int mt = 0; mt < 4; ++mt)
            #pragma unroll
            for (int nt = 0; nt < 4; ++nt)
                acc[mt][nt] = __builtin_amdgcn_mfma_f32_16x16x32_f16(af[mt], bf[nt], acc[mt][nt], 0, 0, 0);
        __syncthreads();
    }

    #pragma unroll
    for (int mt = 0; mt < 4; ++mt) {
        float sqi[4];
        #pragma unroll
        for (int r = 0; r < 4; ++r)
            sqi[r] = sq[base + I0 + wr * 64 + mt * 16 + (lane >> 4) * 4 + r];
        float vmax[4] = {0.0f, 0.0f, 0.0f, 0.0f};
        #pragma unroll
        for (int nt = 0; nt < 4; ++nt) {
            const float sqj = sq[base + J0 + wc * 64 + nt * 16 + (lane & 15)];
            #pragma unroll
            for (int r = 0; r < 4; ++r) {
                const float d2 = sqi[r] + sqj - 2.0f * acc[mt][nt][r];
                vmax[r] = fmaxf(vmax[r], sqrtf(fmaxf(d2, 1e-12f)));
            }
        }
        #pragma unroll
        for (int r = 0; r < 4; ++r) {
            float v = vmax[r];
            v = fmaxf(v, __shfl_xor(v, 1, 64));
            v = fmaxf(v, __shfl_xor(v, 2, 64));
            v = fmaxf(v, __shfl_xor(v, 4, 64));
            v = fmaxf(v, __shfl_xor(v, 8, 64));
            if ((lane & 15) == 0)
                atomicMax((unsigned int*)&m[base + I0 + wr * 64 + mt * 16 + (lane >> 4) * 4 + r],
                          __float_as_uint(v));
        }
    }
}

extern "C" void kernel_launch(void* const* d_in, const int* in_sizes, int n_in,
                              void* d_out, int out_size, void* d_ws, size_t ws_size,
                              hipStream_t stream)
{
    const float* x     = (const float*)d_in[0];
    const float* gamma = (const float*)d_in[1];
    const float* beta  = (const float*)d_in[2];
    const float* w1    = (const float*)d_in[3];
    const float* b1    = (const float*)d_in[4];
    const float* w2    = (const float*)d_in[5];
    const float* b2    = (const float*)d_in[6];
    const float* w3    = (const float*)d_in[7];
    const float* b3    = (const float*)d_in[8];
    const float* w4    = (const float*)d_in[9];
    const float* b4    = (const float*)d_in[10];
    float* out = (float*)d_out;
    float* ws  = (float*)d_ws;

    // ws: avgx[12288] sq[16384] m[16384] | w1T..w4T fp16 | P0,P1 fp16 [BNR*DIM]
    float* avgx = ws;
    float* sq   = ws + 12288;
    float* mbuf = sq + 16384;
    __half* w1T = (__half*)(mbuf + 16384);
    __half* w2T = w1T + (size_t)1536 * 768;
    __half* w3T = w2T + (size_t)768 * 768;
    __half* w4T = w3T + (size_t)768 * 768;
    __half* P0  = w4T + (size_t)768 * 768;            // m1H, later h4H
    __half* P1  = P0 + (size_t)BNR * DIM;             // h3H
    // d_out hosts the two L1-only fp16 operands (dead before L4 writes out)
    __half* Ah  = (__half*)d_out;
    __half* xmH = Ah + (size_t)BNR * DIM;

    hipMemsetAsync(avgx, 0, 12288 * sizeof(float), stream);
    hipMemsetAsync(mbuf, 0, BNR * sizeof(float), stream);
    wconv<<<dim3(12, 24), 256, 0, stream>>>(w1, w1T, 1536, 768);
    wconv<<<dim3(12, 12), 256, 0, stream>>>(w2, w2T, 768, 768);
    wconv<<<dim3(12, 12), 256, 0, stream>>>(w3, w3T, 768, 768);
    wconv<<<dim3(12, 12), 256, 0, stream>>>(w4, w4T, 768, 768);
    avg_kernel<<<dim3(3, NBATCH, 8), 256, 0, stream>>>(x, avgx);
    ln_sig_kernel<<<BNR, 256, 0, stream>>>(x, gamma, beta, avgx, Ah, sq);
    dist16<<<dim3(NBATCH, 8, 8), 256, 0, stream>>>(Ah, sq, mbuf);
    xm_kernel<<<BNR, 256, 0, stream>>>(x, mbuf, xmH);
    // L1: m1 = gelu(cat @ w1 + b1)
    gemm16<true, 0><<<dim3(128, 6), 256, 0, stream>>>(
        Ah, xmH, 2 * DIM, w1T, b1, nullptr, nullptr, P0, nullptr);
    // L2: h3 = m1 * x * gelu(m1 @ w2 + b2)
    gemm16<false, 1><<<dim3(128, 6), 256, 0, stream>>>(
        P0, nullptr, DIM, w2T, b2, x, P0, P1, nullptr);
    // L3: h4 = x * gelu(h3 @ w3 + b3)
    gemm16<false, 2><<<dim3(128, 6), 256, 0, stream>>>(
        P1, nullptr, DIM, w3T, b3, x, nullptr, P0, nullptr);
    // L4: out = gelu(h4 @ w4 + b4)
    gemm16<false, 3><<<dim3(128, 6), 256, 0, stream>>>(
        P0, nullptr, DIM, w4T, b4, x, nullptr, nullptr, out);
}

// Round 5
// 350.601 us; speedup vs baseline: 1.5390x; 1.0059x over previous
//
#include <hip/hip_runtime.h>
#include <hip/hip_fp16.h>
#include <math.h>

#define DIM 768
#define NTOK 1024
#define NBATCH 16
#define BNR (NBATCH * NTOK)   // 16384 rows

typedef _Float16 f16x8 __attribute__((ext_vector_type(8)));
typedef float f32x4 __attribute__((ext_vector_type(4)));

// async global->LDS, 16B per lane, LDS dest = wave-uniform base + lane*16
__device__ __forceinline__ void gl2lds16(const void* g, void* l) {
    __builtin_amdgcn_global_load_lds(
        (const __attribute__((address_space(1))) void*)g,
        (__attribute__((address_space(3))) void*)l, 16, 0, 0);
}

// branch-free exact-gelu: erf via Abramowitz-Stegun 7.1.26 (|abs err| <= 1.5e-7)
__device__ __forceinline__ float gelu_fast(float z) {
    const float s = z * 0.70710678118654752f;
    const float ax = fabsf(s);
    const float t = __builtin_amdgcn_rcpf(1.0f + 0.3275911f * ax);
    const float poly = t * (0.254829592f + t * (-0.284496736f +
                       t * (1.421413741f + t * (-1.453152027f + t * 1.061405429f))));
    const float e = __expf(-ax * ax);
    float erfv = 1.0f - poly * e;
    erfv = copysignf(erfv, s);
    return 0.5f * z * (1.0f + erfv);
}

__device__ __forceinline__ float block_sum(float v, float* sbuf) {
    #pragma unroll
    for (int o = 32; o > 0; o >>= 1) v += __shfl_down(v, o, 64);
    const int lane = threadIdx.x & 63, w = threadIdx.x >> 6;
    if (lane == 0) sbuf[w] = v;
    __syncthreads();
    const float r = sbuf[0] + sbuf[1] + sbuf[2] + sbuf[3];
    __syncthreads();
    return r;
}

// avg over tokens, split 8-way over the token axis for parallelism
__global__ __launch_bounds__(256) void avg_kernel(const float* __restrict__ x,
                                                  float* __restrict__ avgx) {
    const int d = blockIdx.x * 256 + threadIdx.x;
    const int b = blockIdx.y;
    const int n0 = blockIdx.z * 128;
    const float* xp = x + (size_t)b * NTOK * DIM + (size_t)n0 * DIM + d;
    float s = 0.0f;
    for (int n = 0; n < 128; ++n) s += xp[(size_t)n * DIM];
    atomicAdd(&avgx[b * DIM + d], s * (1.0f / NTOK));
}

// LN -> sigmoid -> A = avg_x*sig, stored fp16; sq computed from fp16-rounded A
__global__ __launch_bounds__(256) void ln_sig_kernel(
    const float* __restrict__ x, const float* __restrict__ gamma,
    const float* __restrict__ beta, const float* __restrict__ avgx,
    __half* __restrict__ Ah, float* __restrict__ sq)
{
    __shared__ float sbuf[4];
    const int row = blockIdx.x;
    const int b = row >> 10;
    const int tid = threadIdx.x;
    const float* xr = x + (size_t)row * DIM;
    float v[3];
    #pragma unroll
    for (int i = 0; i < 3; ++i) v[i] = xr[tid + 256 * i];
    const float mu = block_sum(v[0] + v[1] + v[2], sbuf) * (1.0f / DIM);
    float ss = 0.0f;
    #pragma unroll
    for (int i = 0; i < 3; ++i) { const float d = v[i] - mu; ss += d * d; }
    const float var = block_sum(ss, sbuf) * (1.0f / DIM);
    const float rstd = rsqrtf(var + 1e-5f);
    const float* ag = avgx + b * DIM;
    float qs = 0.0f;
    #pragma unroll
    for (int i = 0; i < 3; ++i) {
        const int d = tid + 256 * i;
        const float ln = (v[i] - mu) * rstd * gamma[d] + beta[d];
        const float sg = 1.0f / (1.0f + expf(-ln));
        const float a = ag[d] * sg;
        const __half h = __float2half(a);
        const float ar = __half2float(h);
        Ah[(size_t)row * DIM + d] = h;
        qs += ar * ar;
    }
    const float tot = block_sum(qs, sbuf);
    if (tid == 0) sq[row] = tot;
}

// fp32 [K][N] -> fp16 [N][K] tiled transpose
__global__ __launch_bounds__(256) void wconv(const float* __restrict__ w,
                                             __half* __restrict__ wT, int K, int N)
{
    __shared__ float t[64][65];
    const int k0 = blockIdx.y * 64, n0 = blockIdx.x * 64;
    const int tid = threadIdx.x;
    const int r = tid >> 4, c4 = (tid & 15) * 4;
    #pragma unroll
    for (int p = 0; p < 4; ++p) {
        const int rr = p * 16 + r;
        const float4 v = *(const float4*)&w[(size_t)(k0 + rr) * N + n0 + c4];
        t[rr][c4] = v.x; t[rr][c4 + 1] = v.y; t[rr][c4 + 2] = v.z; t[rr][c4 + 3] = v.w;
    }
    __syncthreads();
    #pragma unroll
    for (int p = 0; p < 4; ++p) {
        const int nn = p * 16 + r;
        ushort4 pk;
        pk.x = __half_as_ushort(__float2half(t[c4 + 0][nn]));
        pk.y = __half_as_ushort(__float2half(t[c4 + 1][nn]));
        pk.z = __half_as_ushort(__float2half(t[c4 + 2][nn]));
        pk.w = __half_as_ushort(__float2half(t[c4 + 3][nn]));
        *(ushort4*)&wT[(size_t)(n0 + nn) * K + k0 + c4] = pk;
    }
}

__global__ __launch_bounds__(256) void xm_kernel(const float* __restrict__ x,
                                                 const float* __restrict__ m,
                                                 __half* __restrict__ xmH) {
    const int row = blockIdx.x;
    const float mv = m[row];
    #pragma unroll
    for (int i = 0; i < 3; ++i) {
        const int d = threadIdx.x + i * 256;
        xmH[(size_t)row * DIM + d] = __float2half(x[(size_t)row * DIM + d] + mv);
    }
}

// ---- MFMA fp16 GEMM, 128x128 tile, BK=32, double-buffered single-barrier K-loop ----
// LDS: logical cell (row, koct) stored at halves offset row*32 + (koct^(row&3))*8.
//  - staging (global_load_lds): lane l -> dest base+l*16 == (row=l>>2, phys oct l&3);
//    lane fetches logical oct (l&3)^((l>>2)&3) -> 64B-coalesced per 4 lanes.
//  - frag ds_read_b128: 64 lanes uniform over all 8 bank-quads.
// K-loop: prefetch tile kt+1 into buf^1, compute on buf, ONE barrier at iter end ->
// the pre-barrier vmcnt(0) drain waits on loads that had the whole compute phase in flight.
// EPI 0: m1=gelu(z)->fp16 ; 1: h3=m1h*x*gelu(z)->fp16 ; 2: h4=x*gelu(z)->fp16 ; 3: out=gelu(z)->fp32
template<int K, bool CAT, int EPI>
__global__ __launch_bounds__(256, 4) void gemm16(
    const __half* __restrict__ A0, const __half* __restrict__ A1,
    const __half* __restrict__ BT, const float* __restrict__ bias,
    const float* __restrict__ xin, const __half* __restrict__ m1h,
    __half* __restrict__ outH, float* __restrict__ outF)
{
    __shared__ _Float16 As[2][128 * 32];
    __shared__ _Float16 Bs[2][128 * 32];
    const int tid = threadIdx.x;
    const int w = tid >> 6, lane = tid & 63;
    const int wu = __builtin_amdgcn_readfirstlane(w);
    const int wr = w >> 1, wc = w & 1;
    const int R0 = blockIdx.x * 128, J0 = blockIdx.y * 128;
    constexpr int rs = CAT ? DIM : K;           // A row stride (halves)
    const int srow = lane >> 2;                 // staging row within 16
    const int sk8 = (((lane & 3) ^ ((lane >> 2) & 3))) * 8;  // swizzled k-offset (halves)
    const int fx = ((lane >> 4) ^ (lane & 3)) * 8;           // frag-read swizzled oct offset
    constexpr int NT = K / 32;

    f32x4 acc[4][4];
    #pragma unroll
    for (int mt = 0; mt < 4; ++mt)
        #pragma unroll
        for (int nt = 0; nt < 4; ++nt) {
            f32x4 z = {0.0f, 0.0f, 0.0f, 0.0f};
            acc[mt][nt] = z;
        }

    auto stage = [&](int buf, int k0) {
        const __half* Ab = (CAT && k0 >= DIM) ? (A1 + (k0 - DIM)) : (A0 + k0);
        #pragma unroll
        for (int i = 0; i < 2; ++i) {
            const int rbase = i * 64 + w * 16;
            const int rbu = i * 64 + wu * 16;
            gl2lds16(Ab + (size_t)(R0 + rbase + srow) * rs + sk8, &As[buf][rbu * 32]);
            gl2lds16(BT + (size_t)(J0 + rbase + srow) * K + k0 + sk8, &Bs[buf][rbu * 32]);
        }
    };

    stage(0, 0);
    __syncthreads();
    #pragma unroll 2
    for (int kt = 0; kt < NT; ++kt) {
        const int cur = kt & 1;
        if (kt + 1 < NT) stage(cur ^ 1, (kt + 1) * 32);
        f16x8 af[4], bf[4];
        #pragma unroll
        for (int mt = 0; mt < 4; ++mt)
            af[mt] = *(const f16x8*)&As[cur][(wr * 64 + mt * 16 + (lane & 15)) * 32 + fx];
        #pragma unroll
        for (int nt = 0; nt < 4; ++nt)
            bf[nt] = *(const f16x8*)&Bs[cur][(wc * 64 + nt * 16 + (lane & 15)) * 32 + fx];
        #pragma unroll
        for (int mt = 0; mt < 4; ++mt)
            #pragma unroll
            for (int nt = 0; nt < 4; ++nt)
                acc[mt][nt] = __builtin_amdgcn_mfma_f32_16x16x32_f16(af[mt], bf[nt], acc[mt][nt], 0, 0, 0);
        __syncthreads();
    }

    // C/D layout: col = lane&15, row = (lane>>4)*4 + reg
    #pragma unroll
    for (int mt = 0; mt < 4; ++mt) {
        #pragma unroll
        for (int nt = 0; nt < 4; ++nt) {
            const int col = J0 + wc * 64 + nt * 16 + (lane & 15);
            const float bv = bias[col];
            #pragma unroll
            for (int r = 0; r < 4; ++r) {
                const int row = R0 + wr * 64 + mt * 16 + (lane >> 4) * 4 + r;
                const size_t off = (size_t)row * DIM + col;
                const float g = gelu_fast(acc[mt][nt][r] + bv);
                if (EPI == 0) {
                    outH[off] = __float2half(g);
                } else if (EPI == 1) {
                    outH[off] = __float2half(__half2float(m1h[off]) * xin[off] * g);
                } else if (EPI == 2) {
                    outH[off] = __float2half(xin[off] * g);
                } else {
                    outF[off] = g;
                }
            }
        }
    }
}

// dist row-max: 128x128 tiles, dbuf single-barrier K-loop; sqrt hoisted out of inner loop
__global__ __launch_bounds__(256, 4) void dist16(const __half* __restrict__ Ah,
                                                 const float* __restrict__ sq,
                                                 float* __restrict__ m)
{
    __shared__ _Float16 As[2][128 * 32];
    __shared__ _Float16 Bs[2][128 * 32];
    const int tid = threadIdx.x;
    const int w = tid >> 6, lane = tid & 63;
    const int wu = __builtin_amdgcn_readfirstlane(w);
    const int wr = w >> 1, wc = w & 1;
    const int base = blockIdx.x * NTOK;
    const int I0 = blockIdx.y * 128, J0 = blockIdx.z * 128;
    const int srow = lane >> 2;
    const int sk8 = (((lane & 3) ^ ((lane >> 2) & 3))) * 8;
    const int fx = ((lane >> 4) ^ (lane & 3)) * 8;
    constexpr int NT = DIM / 32;

    f32x4 acc[4][4];
    #pragma unroll
    for (int mt = 0; mt < 4; ++mt)
        #pragma unroll
        for (int nt = 0; nt < 4; ++nt) {
            f32x4 z = {0.0f, 0.0f, 0.0f, 0.0f};
            acc[mt][nt] = z;
        }

    auto stage = [&](int buf, int k0) {
        #pragma unroll
        for (int i = 0; i < 2; ++i) {
            const int rbase = i * 64 + w * 16;
            const int rbu = i * 64 + wu * 16;
            gl2lds16(Ah + (size_t)(base + I0 + rbase + srow) * DIM + k0 + sk8, &As[buf][rbu * 32]);
            gl2lds16(Ah + (size_t)(base + J0 + rbase + srow) * DIM + k0 + sk8, &Bs[buf][rbu * 32]);
        }
    };

    stage(0, 0);
    __syncthreads();
    #pragma unroll 2
    for (int kt = 0; kt < NT; ++kt) {
        const int cur = kt & 1;
        if (kt + 1 < NT) stage(cur ^ 1, (kt + 1) * 32);
        f16x8 af[4], bf[4];
        #pragma unroll
        for (int mt = 0; mt < 4; ++mt)
            af[mt] = *(const f16x8*)&As[cur][(wr * 64 + mt * 16 + (lane & 15)) * 32 + fx];
        #pragma unroll
        for (int nt = 0; nt < 4; ++nt)
            bf[nt] = *(const f16x8*)&Bs[cur][(wc * 64 + nt * 16 + (lane & 15)) * 32 + fx];
        #pragma unroll
        for (int mt = 0; mt < 4; ++mt)
            #pragma unroll
            for (int nt = 0; nt < 4; ++nt)
                acc[mt][nt] = __builtin_amdgcn_mfma_f32_16x16x32_f16(af[mt], bf[nt], acc[mt][nt], 0, 0, 0);
        __syncthreads();
    }

    #pragma unroll
    for (int mt = 0; mt < 4; ++mt) {
        float sqi[4];
        #pragma unroll
        for (int r = 0; r < 4; ++r)
            sqi[r] = sq[base + I0 + wr * 64 + mt * 16 + (lane >> 4) * 4 + r];
        float vmax[4] = {-1e30f, -1e30f, -1e30f, -1e30f};
        #pragma unroll
        for (int nt = 0; nt < 4; ++nt) {
            const float sqj = sq[base + J0 + wc * 64 + nt * 16 + (lane & 15)];
            #pragma unroll
            for (int r = 0; r < 4; ++r)
                vmax[r] = fmaxf(vmax[r], sqi[r] + sqj - 2.0f * acc[mt][nt][r]);
        }
        #pragma unroll
        for (int r = 0; r < 4; ++r) {
            float v = vmax[r];
            v = fmaxf(v, __shfl_xor(v, 1, 64));
            v = fmaxf(v, __shfl_xor(v, 2, 64));
            v = fmaxf(v, __shfl_xor(v, 4, 64));
            v = fmaxf(v, __shfl_xor(v, 8, 64));
            if ((lane & 15) == 0) {
                const float d = sqrtf(fmaxf(v, 1e-12f));   // max commutes with monotone sqrt
                atomicMax((unsigned int*)&m[base + I0 + wr * 64 + mt * 16 + (lane >> 4) * 4 + r],
                          __float_as_uint(d));
            }
        }
    }
}

extern "C" void kernel_launch(void* const* d_in, const int* in_sizes, int n_in,
                              void* d_out, int out_size, void* d_ws, size_t ws_size,
                              hipStream_t stream)
{
    const float* x     = (const float*)d_in[0];
    const float* gamma = (const float*)d_in[1];
    const float* beta  = (const float*)d_in[2];
    const float* w1    = (const float*)d_in[3];
    const float* b1    = (const float*)d_in[4];
    const float* w2    = (const float*)d_in[5];
    const float* b2    = (const float*)d_in[6];
    const float* w3    = (const float*)d_in[7];
    const float* b3    = (const float*)d_in[8];
    const float* w4    = (const float*)d_in[9];
    const float* b4    = (const float*)d_in[10];
    float* out = (float*)d_out;
    float* ws  = (float*)d_ws;

    // ws: avgx[12288] sq[16384] m[16384] | w1T..w4T fp16 | P0,P1 fp16 [BNR*DIM]
    float* avgx = ws;
    float* sq   = ws + 12288;
    float* mbuf = sq + 16384;
    __half* w1T = (__half*)(mbuf + 16384);
    __half* w2T = w1T + (size_t)1536 * 768;
    __half* w3T = w2T + (size_t)768 * 768;
    __half* w4T = w3T + (size_t)768 * 768;
    __half* P0  = w4T + (size_t)768 * 768;            // m1H, later h4H
    __half* P1  = P0 + (size_t)BNR * DIM;             // h3H
    // d_out hosts the two L1-only fp16 operands (dead before L4 writes out)
    __half* Ah  = (__half*)d_out;
    __half* xmH = Ah + (size_t)BNR * DIM;

    hipMemsetAsync(avgx, 0, 12288 * sizeof(float), stream);
    hipMemsetAsync(mbuf, 0, BNR * sizeof(float), stream);
    wconv<<<dim3(12, 24), 256, 0, stream>>>(w1, w1T, 1536, 768);
    wconv<<<dim3(12, 12), 256, 0, stream>>>(w2, w2T, 768, 768);
    wconv<<<dim3(12, 12), 256, 0, stream>>>(w3, w3T, 768, 768);
    wconv<<<dim3(12, 12), 256, 0, stream>>>(w4, w4T, 768, 768);
    avg_kernel<<<dim3(3, NBATCH, 8), 256, 0, stream>>>(x, avgx);
    ln_sig_kernel<<<BNR, 256, 0, stream>>>(x, gamma, beta, avgx, Ah, sq);
    dist16<<<dim3(NBATCH, 8, 8), 256, 0, stream>>>(Ah, sq, mbuf);
    xm_kernel<<<BNR, 256, 0, stream>>>(x, mbuf, xmH);
    // L1: m1 = gelu(cat @ w1 + b1)
    gemm16<1536, true, 0><<<dim3(128, 6), 256, 0, stream>>>(
        Ah, xmH, w1T, b1, nullptr, nullptr, P0, nullptr);
    // L2: h3 = m1 * x * gelu(m1 @ w2 + b2)
    gemm16<768, false, 1><<<dim3(128, 6), 256, 0, stream>>>(
        P0, nullptr, w2T, b2, x, P0, P1, nullptr);
    // L3: h4 = x * gelu(h3 @ w3 + b3)
    gemm16<768, false, 2><<<dim3(128, 6), 256, 0, stream>>>(
        P1, nullptr, w3T, b3, x, nullptr, P0, nullptr);
    // L4: out = gelu(h4 @ w4 + b4)
    gemm16<768, false, 3><<<dim3(128, 6), 256, 0, stream>>>(
        P0, nullptr, w4T, b4, x, nullptr, nullptr, out);
}